// Round 1
// baseline (22054.599 us; speedup 1.0000x reference)
//
#include <hip/hip_runtime.h>

#define BATCH 32
#define PIX   3072
#define NEU   4096
#define STEPS 99   // reference runs NUM_STEPS - 1 = 99 update iterations

__device__ __forceinline__ float softt(float u, float lam) {
    return u > lam ? u - lam : (u < -lam ? u + lam : 0.0f);
}

// b = x @ phi, u = 0, a = 0
// grid (64, 8), block 256: n = bx*64 + (tid&63), bi = by*4 + (tid>>6)
__global__ void lca_init(const float* __restrict__ x, const float* __restrict__ phi,
                         float* __restrict__ b, float* __restrict__ u,
                         float* __restrict__ a) {
    const int n  = blockIdx.x * 64 + (threadIdx.x & 63);
    const int bi = blockIdx.y * 4 + (threadIdx.x >> 6);
    const float* xr = x + bi * PIX;
    float acc = 0.f;
    #pragma unroll 4
    for (int p = 0; p < PIX; ++p)
        acc = fmaf(xr[p], phi[p * NEU + n], acc);
    const int idx = bi * NEU + n;
    b[idx] = acc;
    u[idx] = 0.f;
    a[idx] = 0.f;
}

// s[bi,p] = sum_n a[bi,n] * phi[p,n]   (both K-contiguous: lane-split K)
// grid (96, 32), block 256 (4 waves); wave w handles bi=blockIdx.y, p0=(bx*4+w)*8
__global__ void lca_s(const float* __restrict__ a, const float* __restrict__ phi,
                      float* __restrict__ s) {
    const int lane = threadIdx.x & 63;
    const int w    = threadIdx.x >> 6;
    const int bi   = blockIdx.y;
    const int p0   = (blockIdx.x * 4 + w) * 8;
    const float* ar = a + bi * NEU;
    float acc[8] = {0.f, 0.f, 0.f, 0.f, 0.f, 0.f, 0.f, 0.f};
    for (int i = 0; i < NEU / 64; ++i) {
        const int n = i * 64 + lane;
        const float av = ar[n];
        #pragma unroll
        for (int j = 0; j < 8; ++j)
            acc[j] = fmaf(av, phi[(p0 + j) * NEU + n], acc[j]);
    }
    float out = 0.f;
    #pragma unroll
    for (int j = 0; j < 8; ++j) {
        float v = acc[j];
        v += __shfl_xor(v, 1, 64);
        v += __shfl_xor(v, 2, 64);
        v += __shfl_xor(v, 4, 64);
        v += __shfl_xor(v, 8, 64);
        v += __shfl_xor(v, 16, 64);
        v += __shfl_xor(v, 32, 64);
        if (lane == j) out = v;
    }
    if (lane < 8) s[bi * PIX + p0 + lane] = out;
}

// t[b,n] = sum_p s[b,p] * phi[p,n]; then u += eta*(b - t + a - u); a = soft(u)
// grid (64, 4), block 512 (8 waves): n = bx*64 + (tid&63), b = by*8 + (tid>>6)
__global__ void lca_t(const float* __restrict__ s, const float* __restrict__ phi,
                      const float* __restrict__ b, float* __restrict__ u,
                      float* __restrict__ a, const float* __restrict__ lamp) {
    __shared__ float ls[8 * 256];
    const int n    = blockIdx.x * 64 + (threadIdx.x & 63);
    const int slot = threadIdx.x >> 6;          // 0..7
    const int bb   = blockIdx.y * 8 + slot;     // batch index
    float acc = 0.f;
    for (int c = 0; c < PIX; c += 256) {
        __syncthreads();
        #pragma unroll
        for (int e = threadIdx.x; e < 8 * 256; e += 512) {
            const int r = e >> 8, p = e & 255;
            ls[e] = s[(blockIdx.y * 8 + r) * PIX + c + p];
        }
        __syncthreads();
        const float* lrow = ls + slot * 256;
        #pragma unroll 8
        for (int p = 0; p < 256; ++p)
            acc = fmaf(lrow[p], phi[(c + p) * NEU + n], acc);
    }
    const float lam = lamp[0];
    const int idx = bb * NEU + n;
    const float uo = u[idx];
    const float du = b[idx] - acc + a[idx] - uo;
    const float un = fmaf(0.001f / 0.03f, du, uo);
    u[idx] = un;
    a[idx] = softt(un, lam);
}

extern "C" void kernel_launch(void* const* d_in, const int* in_sizes, int n_in,
                              void* d_out, int out_size, void* d_ws, size_t ws_size,
                              hipStream_t stream) {
    const float* x    = (const float*)d_in[0];
    const float* phi  = (const float*)d_in[1];
    const float* lamp = (const float*)d_in[2];
    float* a  = (float*)d_out;
    float* ws = (float*)d_ws;
    float* b  = ws;                       // 32*4096
    float* u  = ws + BATCH * NEU;         // 32*4096
    float* s  = ws + 2 * BATCH * NEU;     // 32*3072

    lca_init<<<dim3(64, 8), 256, 0, stream>>>(x, phi, b, u, a);
    for (int it = 0; it < STEPS; ++it) {
        lca_s<<<dim3(96, 32), 256, 0, stream>>>(a, phi, s);
        lca_t<<<dim3(64, 4), 512, 0, stream>>>(s, phi, b, u, a, lamp);
    }
}

// Round 2
// 1568.767 us; speedup vs baseline: 14.0586x; 14.0586x over previous
//
#include <hip/hip_runtime.h>

#define BATCH 32
#define PIX   3072
#define NEU   4096
#define STEPS 99           // reference runs NUM_STEPS-1 = 99 update iterations
#define ETA   (0.001f / 0.03f)

typedef __bf16 bf16x8 __attribute__((ext_vector_type(8)));
typedef float  f32x4  __attribute__((ext_vector_type(4)));

__device__ __forceinline__ float softt(float u, float lam) {
    return u > lam ? u - lam : (u < -lam ? u + lam : 0.0f);
}

// fp32 -> bf16 round-to-nearest-even
__device__ __forceinline__ unsigned short f2b(float f) {
    unsigned int u = __builtin_bit_cast(unsigned int, f);
    u = (u + 0x7FFFu + ((u >> 16) & 1u)) >> 16;
    return (unsigned short)u;
}

__device__ __forceinline__ bf16x8 ldfrag_g(const unsigned short* p) {
    uint4 v = *(const uint4*)p;
    return __builtin_bit_cast(bf16x8, v);
}

// ---------------------------------------------------------------------------
// φ (fp32 [PIX][NEU]) -> φT (bf16 [NEU][PIX]).  64x64 tiles via LDS.
// grid (NEU/64, PIX/64), block 256
__global__ void transp(const float* __restrict__ phi, unsigned short* __restrict__ phiT) {
    __shared__ float t[64][65];
    const int n0 = blockIdx.x * 64, p0 = blockIdx.y * 64;
    const int tid = threadIdx.x;
    #pragma unroll
    for (int pass = 0; pass < 4; ++pass) {
        const int r  = pass * 16 + (tid >> 4);
        const int c4 = (tid & 15) * 4;
        float4 v = *(const float4*)(phi + (size_t)(p0 + r) * NEU + n0 + c4);
        t[r][c4 + 0] = v.x; t[r][c4 + 1] = v.y; t[r][c4 + 2] = v.z; t[r][c4 + 3] = v.w;
    }
    __syncthreads();
    #pragma unroll
    for (int pass = 0; pass < 2; ++pass) {
        const int cp = pass * 32 + (tid >> 3);   // n-column -> φT row
        const int p8 = (tid & 7) * 8;            // 8 consecutive p
        unsigned int w0 = (unsigned int)f2b(t[p8 + 0][cp]) | ((unsigned int)f2b(t[p8 + 1][cp]) << 16);
        unsigned int w1 = (unsigned int)f2b(t[p8 + 2][cp]) | ((unsigned int)f2b(t[p8 + 3][cp]) << 16);
        unsigned int w2 = (unsigned int)f2b(t[p8 + 4][cp]) | ((unsigned int)f2b(t[p8 + 5][cp]) << 16);
        unsigned int w3 = (unsigned int)f2b(t[p8 + 6][cp]) | ((unsigned int)f2b(t[p8 + 7][cp]) << 16);
        uint4 o = make_uint4(w0, w1, w2, w3);
        *(uint4*)(phiT + (size_t)(n0 + cp) * PIX + p0 + p8) = o;
    }
}

// ---------------------------------------------------------------------------
// G[m][n] = sum_k phiT[m][k]*phiT[n][k]  (= φᵀφ, symmetric), bf16 output.
// grid (32,32), block 256 (4 waves, each 64x64 via 4x4 of 16x16x32 mfma), BK=32
__global__ void gemm_G(const unsigned short* __restrict__ phiT, unsigned short* __restrict__ G) {
    __shared__ __align__(16) unsigned short lds[2][128 * 32];
    const int m0 = blockIdx.y * 128, n0 = blockIdx.x * 128;
    const int tid  = threadIdx.x;
    const int lane = tid & 63, w = tid >> 6;
    const int wm = (w & 1) * 64, wn = (w >> 1) * 64;
    const int q8 = (lane >> 4) * 8, l15 = lane & 15;
    f32x4 acc[4][4] = {};
    for (int k0 = 0; k0 < PIX; k0 += 32) {
        __syncthreads();
        #pragma unroll
        for (int it = 0; it < 2; ++it) {
            const int id = tid + 256 * it;       // 0..511
            const int row = id >> 2, q = id & 3;
            uint4 va = *(const uint4*)(phiT + (size_t)(m0 + row) * PIX + k0 + q * 8);
            *(uint4*)(&lds[0][row * 32 + q * 8]) = va;
            uint4 vb = *(const uint4*)(phiT + (size_t)(n0 + row) * PIX + k0 + q * 8);
            *(uint4*)(&lds[1][row * 32 + q * 8]) = vb;
        }
        __syncthreads();
        bf16x8 af[4], bfr[4];
        #pragma unroll
        for (int i = 0; i < 4; ++i) {
            af[i]  = *(const bf16x8*)(&lds[0][(wm + i * 16 + l15) * 32 + q8]);
            bfr[i] = *(const bf16x8*)(&lds[1][(wn + i * 16 + l15) * 32 + q8]);
        }
        #pragma unroll
        for (int i = 0; i < 4; ++i)
            #pragma unroll
            for (int j = 0; j < 4; ++j)
                acc[i][j] = __builtin_amdgcn_mfma_f32_16x16x32_bf16(af[i], bfr[j], acc[i][j], 0, 0, 0);
    }
    const int q = lane >> 4;
    #pragma unroll
    for (int i = 0; i < 4; ++i)
        #pragma unroll
        for (int j = 0; j < 4; ++j)
            #pragma unroll
            for (int r = 0; r < 4; ++r) {
                const int gm = m0 + wm + i * 16 + q * 4 + r;
                const int gn = n0 + wn + j * 16 + l15;
                G[(size_t)gm * NEU + gn] = f2b(acc[i][j][r]);
            }
}

// ---------------------------------------------------------------------------
// b = x @ phi  (B[k][n] = phiT[n][k] rows), plus zero-init of u, a, ab.
// grid 256 (16-col strips), block 512 (8 waves, 8-way split-K over PIX)
__global__ void lca_binit(const float* __restrict__ x, const unsigned short* __restrict__ phiT,
                          float* __restrict__ b, float* __restrict__ u,
                          float* __restrict__ a, unsigned short* __restrict__ ab) {
    __shared__ float red[8 * 512];
    const int tid = threadIdx.x;
    const int lane = tid & 63, w = tid >> 6;
    const int n0 = blockIdx.x * 16;
    const int kbase = w * (PIX / 8);             // 384
    const int q8 = (lane >> 4) * 8, l15 = lane & 15;
    f32x4 acc[2] = {};
    const unsigned short* Brow = phiT + (size_t)(n0 + l15) * PIX + kbase + q8;
    const float* X0 = x + (size_t)l15 * PIX + kbase + q8;
    const float* X1 = x + (size_t)(16 + l15) * PIX + kbase + q8;
    #pragma unroll 4
    for (int kk = 0; kk < PIX / 8; kk += 32) {
        bf16x8 bg = ldfrag_g(Brow + kk);
        float4 xa0 = *(const float4*)(X0 + kk), xb0 = *(const float4*)(X0 + kk + 4);
        float4 xa1 = *(const float4*)(X1 + kk), xb1 = *(const float4*)(X1 + kk + 4);
        bf16x8 a0, a1;
        a0[0]=(__bf16)xa0.x; a0[1]=(__bf16)xa0.y; a0[2]=(__bf16)xa0.z; a0[3]=(__bf16)xa0.w;
        a0[4]=(__bf16)xb0.x; a0[5]=(__bf16)xb0.y; a0[6]=(__bf16)xb0.z; a0[7]=(__bf16)xb0.w;
        a1[0]=(__bf16)xa1.x; a1[1]=(__bf16)xa1.y; a1[2]=(__bf16)xa1.z; a1[3]=(__bf16)xa1.w;
        a1[4]=(__bf16)xb1.x; a1[5]=(__bf16)xb1.y; a1[6]=(__bf16)xb1.z; a1[7]=(__bf16)xb1.w;
        acc[0] = __builtin_amdgcn_mfma_f32_16x16x32_bf16(a0, bg, acc[0], 0, 0, 0);
        acc[1] = __builtin_amdgcn_mfma_f32_16x16x32_bf16(a1, bg, acc[1], 0, 0, 0);
    }
    const int q = lane >> 4;
    #pragma unroll
    for (int mt = 0; mt < 2; ++mt)
        #pragma unroll
        for (int r = 0; r < 4; ++r)
            red[w * 512 + (mt * 16 + q * 4 + r) * 16 + l15] = acc[mt][r];
    __syncthreads();
    float s = 0.f;
    #pragma unroll
    for (int w8 = 0; w8 < 8; ++w8) s += red[w8 * 512 + tid];
    const int m = tid >> 4, n = n0 + (tid & 15);
    const size_t idx = (size_t)m * NEU + n;
    b[idx] = s; u[idx] = 0.f; a[idx] = 0.f; ab[idx] = 0;
}

// ---------------------------------------------------------------------------
// One LCA step: acc = a @ G (G symmetric: B[k][n] = G[n][k] rows), then
// u += ETA*(b - acc + a - u); a = soft(u).  grid 256, block 512 (8-way split-K)
__global__ void lca_step(const unsigned short* __restrict__ G, const float* __restrict__ b,
                         float* __restrict__ u, float* __restrict__ a,
                         unsigned short* __restrict__ ab, const float* __restrict__ lamp) {
    __shared__ float red[8 * 512];
    const int tid = threadIdx.x;
    const int lane = tid & 63, w = tid >> 6;
    const int n0 = blockIdx.x * 16;
    const int kbase = w * (NEU / 8);             // 512
    const int q8 = (lane >> 4) * 8, l15 = lane & 15;
    f32x4 acc[2] = {};
    const unsigned short* Grow = G + (size_t)(n0 + l15) * NEU + kbase + q8;
    const unsigned short* A0 = ab + (size_t)l15 * NEU + kbase + q8;
    const unsigned short* A1 = ab + (size_t)(16 + l15) * NEU + kbase + q8;
    #pragma unroll 4
    for (int kk = 0; kk < NEU / 8; kk += 32) {
        bf16x8 bg = ldfrag_g(Grow + kk);
        bf16x8 a0 = ldfrag_g(A0 + kk);
        bf16x8 a1 = ldfrag_g(A1 + kk);
        acc[0] = __builtin_amdgcn_mfma_f32_16x16x32_bf16(a0, bg, acc[0], 0, 0, 0);
        acc[1] = __builtin_amdgcn_mfma_f32_16x16x32_bf16(a1, bg, acc[1], 0, 0, 0);
    }
    const int q = lane >> 4;
    #pragma unroll
    for (int mt = 0; mt < 2; ++mt)
        #pragma unroll
        for (int r = 0; r < 4; ++r)
            red[w * 512 + (mt * 16 + q * 4 + r) * 16 + l15] = acc[mt][r];
    __syncthreads();
    float s = 0.f;
    #pragma unroll
    for (int w8 = 0; w8 < 8; ++w8) s += red[w8 * 512 + tid];
    const int m = tid >> 4, n = n0 + (tid & 15);
    const size_t idx = (size_t)m * NEU + n;
    const float uo = u[idx];
    const float du = b[idx] - s + a[idx] - uo;
    const float un = fmaf(ETA, du, uo);
    u[idx] = un;
    const float an = softt(un, lamp[0]);
    a[idx] = an;
    ab[idx] = f2b(an);
}

// ===========================================================================
// Fallback fp32 path (round-1, known correct) for small ws_size
// ===========================================================================
__global__ void lca_init_f(const float* __restrict__ x, const float* __restrict__ phi,
                           float* __restrict__ b, float* __restrict__ u,
                           float* __restrict__ a) {
    const int n  = blockIdx.x * 64 + (threadIdx.x & 63);
    const int bi = blockIdx.y * 4 + (threadIdx.x >> 6);
    const float* xr = x + bi * PIX;
    float acc = 0.f;
    #pragma unroll 4
    for (int p = 0; p < PIX; ++p) acc = fmaf(xr[p], phi[p * NEU + n], acc);
    const int idx = bi * NEU + n;
    b[idx] = acc; u[idx] = 0.f; a[idx] = 0.f;
}
__global__ void lca_s_f(const float* __restrict__ a, const float* __restrict__ phi,
                        float* __restrict__ s) {
    const int lane = threadIdx.x & 63, w = threadIdx.x >> 6;
    const int bi = blockIdx.y, p0 = (blockIdx.x * 4 + w) * 8;
    const float* ar = a + bi * NEU;
    float acc[8] = {};
    for (int i = 0; i < NEU / 64; ++i) {
        const int n = i * 64 + lane;
        const float av = ar[n];
        #pragma unroll
        for (int j = 0; j < 8; ++j) acc[j] = fmaf(av, phi[(p0 + j) * NEU + n], acc[j]);
    }
    float out = 0.f;
    #pragma unroll
    for (int j = 0; j < 8; ++j) {
        float v = acc[j];
        v += __shfl_xor(v, 1, 64); v += __shfl_xor(v, 2, 64); v += __shfl_xor(v, 4, 64);
        v += __shfl_xor(v, 8, 64); v += __shfl_xor(v, 16, 64); v += __shfl_xor(v, 32, 64);
        if (lane == j) out = v;
    }
    if (lane < 8) s[bi * PIX + p0 + lane] = out;
}
__global__ void lca_t_f(const float* __restrict__ s, const float* __restrict__ phi,
                        const float* __restrict__ b, float* __restrict__ u,
                        float* __restrict__ a, const float* __restrict__ lamp) {
    __shared__ float ls[8 * 256];
    const int n = blockIdx.x * 64 + (threadIdx.x & 63);
    const int slot = threadIdx.x >> 6;
    const int bb = blockIdx.y * 8 + slot;
    float acc = 0.f;
    for (int c = 0; c < PIX; c += 256) {
        __syncthreads();
        for (int e = threadIdx.x; e < 8 * 256; e += 512) {
            const int r = e >> 8, p = e & 255;
            ls[e] = s[(blockIdx.y * 8 + r) * PIX + c + p];
        }
        __syncthreads();
        const float* lrow = ls + slot * 256;
        #pragma unroll 8
        for (int p = 0; p < 256; ++p) acc = fmaf(lrow[p], phi[(c + p) * NEU + n], acc);
    }
    const float lam = lamp[0];
    const int idx = bb * NEU + n;
    const float uo = u[idx];
    const float du = b[idx] - acc + a[idx] - uo;
    const float un = fmaf(ETA, du, uo);
    u[idx] = un; a[idx] = softt(un, lam);
}

// ===========================================================================
extern "C" void kernel_launch(void* const* d_in, const int* in_sizes, int n_in,
                              void* d_out, int out_size, void* d_ws, size_t ws_size,
                              hipStream_t stream) {
    const float* x    = (const float*)d_in[0];
    const float* phi  = (const float*)d_in[1];
    const float* lamp = (const float*)d_in[2];
    float* a = (float*)d_out;
    char* ws = (char*)d_ws;

    const size_t PHIT_OFF = 0;
    const size_t G_OFF    = PHIT_OFF + (size_t)NEU * PIX * 2;       // 25165824
    const size_t B_OFF    = G_OFF    + (size_t)NEU * NEU * 2;       // 58720256
    const size_t U_OFF    = B_OFF    + (size_t)BATCH * NEU * 4;
    const size_t AB_OFF   = U_OFF    + (size_t)BATCH * NEU * 4;
    const size_t NEED     = AB_OFF   + (size_t)BATCH * NEU * 2;     // ~60.03 MB

    if (ws_size >= NEED) {
        unsigned short* phiT = (unsigned short*)(ws + PHIT_OFF);
        unsigned short* G    = (unsigned short*)(ws + G_OFF);
        float* b  = (float*)(ws + B_OFF);
        float* u  = (float*)(ws + U_OFF);
        unsigned short* ab = (unsigned short*)(ws + AB_OFF);

        transp<<<dim3(NEU / 64, PIX / 64), 256, 0, stream>>>(phi, phiT);
        gemm_G<<<dim3(32, 32), 256, 0, stream>>>(phiT, G);
        lca_binit<<<256, 512, 0, stream>>>(x, phiT, b, u, a, ab);
        for (int it = 0; it < STEPS; ++it)
            lca_step<<<256, 512, 0, stream>>>(G, b, u, a, ab, lamp);
    } else {
        float* fws = (float*)d_ws;
        float* b = fws;
        float* u = fws + BATCH * NEU;
        float* s = fws + 2 * BATCH * NEU;
        lca_init_f<<<dim3(64, 8), 256, 0, stream>>>(x, phi, b, u, a);
        for (int it = 0; it < STEPS; ++it) {
            lca_s_f<<<dim3(96, 32), 256, 0, stream>>>(a, phi, s);
            lca_t_f<<<dim3(64, 4), 512, 0, stream>>>(s, phi, b, u, a, lamp);
        }
    }
}